// Round 1
// 539.826 us; speedup vs baseline: 1.0021x; 1.0021x over previous
//
#include <hip/hip_runtime.h>
#include <hip/hip_bf16.h>

#define BB 4
#define SS 512
#define DD 512
#define HH 8
#define DK 64
#define PP 16
#define TSZ 33   // 2P+1

typedef __bf16 bf16x8 __attribute__((ext_vector_type(8)));
typedef __bf16 bf16x4 __attribute__((ext_vector_type(4)));
typedef float  f32x4  __attribute__((ext_vector_type(4)));

union U8 { bf16x8 v; int u[4]; };

__device__ inline bf16x8 cvt8(const float* __restrict__ p) {
    f32x4 a = *(const f32x4*)p;
    f32x4 b = *(const f32x4*)(p + 4);
    bf16x8 r;
    r[0] = (__bf16)a[0]; r[1] = (__bf16)a[1]; r[2] = (__bf16)a[2]; r[3] = (__bf16)a[3];
    r[4] = (__bf16)b[0]; r[5] = (__bf16)b[1]; r[6] = (__bf16)b[2]; r[7] = (__bf16)b[3];
    return r;
}

// ---------------- prep: table mean + Wo -> bf16 ----------------
__global__ void prep_kernel(const float* __restrict__ rel_table, float* __restrict__ Tm,
                            const float* __restrict__ Wo, __bf16* __restrict__ Wobf) {
    int b = blockIdx.x, t = threadIdx.x;
    if (b == 0) {
        if (t < TSZ) {
            float s = 0.f;
            for (int e = 0; e < DK; ++e) s += rel_table[t * DK + e];
            Tm[t] = s * (1.f / DK);
        }
    } else {
        int idx = ((b - 1) * 256 + t) * 8;   // 128 blocks * 256 thr * 8 = 512*512
        *(bf16x8*)(Wobf + idx) = cvt8(Wo + idx);
    }
}

// ---------------- QKV projection (MFMA), all three in one dispatch ----------------
__global__ void proj_mfma_kernel(const float* __restrict__ X0, const float* __restrict__ X1,
                                 const float* __restrict__ X2,
                                 const float* __restrict__ W0, const float* __restrict__ W1,
                                 const float* __restrict__ W2,
                                 const float* __restrict__ B0, const float* __restrict__ B1,
                                 const float* __restrict__ B2,
                                 __bf16* __restrict__ O0, __bf16* __restrict__ O1,
                                 __bf16* __restrict__ O2) {
    int z = blockIdx.z;
    const float* X = (z == 0) ? X0 : (z == 1) ? X1 : X2;
    const float* W = (z == 0) ? W0 : (z == 1) ? W1 : W2;
    const float* bias = (z == 0) ? B0 : (z == 1) ? B1 : B2;
    __bf16* out = (z == 0) ? O0 : (z == 1) ? O1 : O2;
    int mode = (z == 2);

    int lane = threadIdx.x, wave = threadIdx.y;
    int tm = blockIdx.y * 4 + wave;
    int tn = blockIdx.x;
    int m = lane & 15, quad = lane >> 4;

    const float* arow = X + (size_t)(tm * 16 + m) * DD + quad * 8;
    const float* brow = W + (size_t)(tn * 16 + m) * DD + quad * 8;

    f32x4 acc = {0.f, 0.f, 0.f, 0.f};
    for (int k0 = 0; k0 < DD; k0 += 32) {
        bf16x8 a = cvt8(arow + k0);
        bf16x8 b = cvt8(brow + k0);
        acc = __builtin_amdgcn_mfma_f32_16x16x32_bf16(a, b, acc, 0, 0, 0);
    }

    int col = tn * 16 + m;
    int h = col >> 6, dk = col & (DK - 1);
    float bv = bias[col];
#pragma unroll
    for (int r = 0; r < 4; ++r) {
        int rowg = tm * 16 + quad * 4 + r;
        int b = rowg >> 9, i = rowg & (SS - 1);
        float v = acc[r] + bv;
        if (mode == 0)
            out[((size_t)(b * HH + h) * SS + i) * DK + dk] = (__bf16)v;
        else
            out[((size_t)(b * HH + h) * DK + dk) * SS + i] = (__bf16)v;
    }
}

// ---------------- F1: scores + relbias(MFMA, reg-gather) + partial softmax ----------
// grid (jq=4, i0=32, b=4), block (64,8). wave w: head w for scores/softmax,
// j-tile w for bias. ONE barrier. p' stored bf16.
__launch_bounds__(512, 4)
__global__ void f1_kernel(const __bf16* __restrict__ Qbf, const __bf16* __restrict__ Kbf,
                          const int* __restrict__ relpos, const float* __restrict__ Tm,
                          const int* __restrict__ mask, __bf16* __restrict__ pws,
                          float* __restrict__ pm, float* __restrict__ pl) {
    // bias_sh[h][i][j_local]: strides h:2112, i:132 (pad -> max 2-way bank alias)
    __shared__ float bias_sh[8 * 16 * 132];

    int l = threadIdx.x, w = threadIdx.y;
    int jq = blockIdx.x, i0 = blockIdx.y, b = blockIdx.z;
    int m = l & 15, quad = l >> 4;

    // Tmean as bf16 bits, register-resident (lanes 0..32)
    float tmf = Tm[l < TSZ ? l : 0];
    int tmb = (int)__builtin_bit_cast(unsigned short, (__bf16)tmf);

    // ---- bias phase: wave w handles local j-tile w, all h, i = 0..15 ----
    {
        const int ISTR = SS * DK; // 32768
        const int* rbase = relpos + ((size_t)(b * SS + i0 * 16) * SS + jq * 128 + w * 16 + m) * DK + quad * 8;
        // depth-2 prefetch of relpos (HBM latency ~900cy > 1 iter of compute)
        int4 u0 = *(const int4*)(rbase);
        int4 u1 = *(const int4*)(rbase + 4);
        int4 u2 = *(const int4*)(rbase + 32);
        int4 u3 = *(const int4*)(rbase + 36);
        const int* pb1 = rbase + ISTR;
        int4 v0 = *(const int4*)(pb1);
        int4 v1 = *(const int4*)(pb1 + 4);
        int4 v2 = *(const int4*)(pb1 + 32);
        int4 v3 = *(const int4*)(pb1 + 36);
        for (int i = 0; i < 16; ++i) {
            int4 n0, n1, n2, n3;
            if (i < 14) {
                const int* nb = rbase + (i + 2) * ISTR;
                n0 = *(const int4*)(nb);
                n1 = *(const int4*)(nb + 4);
                n2 = *(const int4*)(nb + 32);
                n3 = *(const int4*)(nb + 36);
            }
            // A-frags: Q[h=m&7, i, d]
            const __bf16* qp = Qbf + ((size_t)(b * HH + (m & 7)) * SS + i0 * 16 + i) * DK + quad * 8;
            bf16x8 A0 = *(const bf16x8*)qp;
            bf16x8 A1 = *(const bf16x8*)(qp + 32);
            // B-frags: Tm[clip(idx)] via bpermute LUT
#define LUT(vv) __builtin_amdgcn_ds_bpermute((min(max((vv), -PP), PP) + PP) << 2, tmb)
            U8 Bf0, Bf1;
            Bf0.u[0] = LUT(u0.x) | (LUT(u0.y) << 16);
            Bf0.u[1] = LUT(u0.z) | (LUT(u0.w) << 16);
            Bf0.u[2] = LUT(u1.x) | (LUT(u1.y) << 16);
            Bf0.u[3] = LUT(u1.z) | (LUT(u1.w) << 16);
            Bf1.u[0] = LUT(u2.x) | (LUT(u2.y) << 16);
            Bf1.u[1] = LUT(u2.z) | (LUT(u2.w) << 16);
            Bf1.u[2] = LUT(u3.x) | (LUT(u3.y) << 16);
            Bf1.u[3] = LUT(u3.z) | (LUT(u3.w) << 16);
#undef LUT
            f32x4 accB = {0.f, 0.f, 0.f, 0.f};
            accB = __builtin_amdgcn_mfma_f32_16x16x32_bf16(A0, Bf0.v, accB, 0, 0, 0);
            accB = __builtin_amdgcn_mfma_f32_16x16x32_bf16(A1, Bf1.v, accB, 0, 0, 0);
            if (quad < 2) {
#pragma unroll
                for (int r = 0; r < 4; ++r) {
                    int h = quad * 4 + r;   // 0..7
                    bias_sh[h * 2112 + i * 132 + w * 16 + m] = accB[r];
                }
            }
            u0 = v0; u1 = v1; u2 = v2; u3 = v3;
            v0 = n0; v1 = n1; v2 = n2; v3 = n3;
        }
    }

    // ---- score phase: wave w = head w ----
    const __bf16* qrow = Qbf + ((size_t)(b * HH + w) * SS + i0 * 16 + m) * DK + quad * 8;
    bf16x8 a0 = *(const bf16x8*)qrow;
    bf16x8 a1 = *(const bf16x8*)(qrow + 32);

    f32x4 acc[8];
#pragma unroll
    for (int jt = 0; jt < 8; ++jt) {
        const __bf16* krow = Kbf + ((size_t)(b * HH + w) * SS + jq * 128 + jt * 16 + m) * DK + quad * 8;
        bf16x8 b0 = *(const bf16x8*)krow;
        bf16x8 b1 = *(const bf16x8*)(krow + 32);
        f32x4 c = {0.f, 0.f, 0.f, 0.f};
        c = __builtin_amdgcn_mfma_f32_16x16x32_bf16(a0, b0, c, 0, 0, 0);
        c = __builtin_amdgcn_mfma_f32_16x16x32_bf16(a1, b1, c, 0, 0, 0);
        acc[jt] = c;
    }

    __syncthreads();   // bias_sh ready

    // ---- combine: scale + bias ----
#pragma unroll
    for (int jt = 0; jt < 8; ++jt) {
#pragma unroll
        for (int r = 0; r < 4; ++r) {
            float bv = bias_sh[w * 2112 + (quad * 4 + r) * 132 + jt * 16 + m];
            acc[jt][r] = acc[jt][r] * 0.125f + bv;
        }
    }

    // ---- mask ----
#pragma unroll
    for (int jt = 0; jt < 8; ++jt) {
        int mv = mask[b * SS + jq * 128 + jt * 16 + m];
        if (mv == 0) {
#pragma unroll
            for (int r = 0; r < 4; ++r) acc[jt][r] = -1e9f;
        }
    }

    // ---- partial softmax over this quarter ----
#pragma unroll
    for (int r = 0; r < 4; ++r) {
        float mx = -1e30f;
#pragma unroll
        for (int jt = 0; jt < 8; ++jt) mx = fmaxf(mx, acc[jt][r]);
        mx = fmaxf(mx, __shfl_xor(mx, 1));
        mx = fmaxf(mx, __shfl_xor(mx, 2));
        mx = fmaxf(mx, __shfl_xor(mx, 4));
        mx = fmaxf(mx, __shfl_xor(mx, 8));
        float sum = 0.f;
#pragma unroll
        for (int jt = 0; jt < 8; ++jt) {
            float e = __expf(acc[jt][r] - mx);
            acc[jt][r] = e;
            sum += e;
        }
        sum += __shfl_xor(sum, 1);
        sum += __shfl_xor(sum, 2);
        sum += __shfl_xor(sum, 4);
        sum += __shfl_xor(sum, 8);
        if (m == 0) {
            int row = i0 * 16 + quad * 4 + r;
            pm[((size_t)(b * HH + w) * SS + row) * 4 + jq] = mx;
            pl[((size_t)(b * HH + w) * SS + row) * 4 + jq] = sum;
        }
    }

    // ---- store p' (unnormalized, bf16) ----
#pragma unroll
    for (int jt = 0; jt < 8; ++jt) {
#pragma unroll
        for (int r = 0; r < 4; ++r) {
            pws[((size_t)(b * HH + w) * SS + i0 * 16 + quad * 4 + r) * SS
                + jq * 128 + jt * 16 + m] = (__bf16)acc[jt][r];
        }
    }
}

// ---------------- F2: attn = scl*p' (f32 out) + ctx = P @ V, no LDS staging --------
// p' bf16 row-major IS the MFMA A-frag layout; softmax scale applied on the
// f32 accumulator per j-quarter (scale commutes with the j-contraction).
__launch_bounds__(256, 4)
__global__ void f2_kernel(const __bf16* __restrict__ pws, const float* __restrict__ pm,
                          const float* __restrict__ pl, const __bf16* __restrict__ Vt,
                          float* __restrict__ attn, __bf16* __restrict__ ctx_bsd) {
    __shared__ float scl[4][16];

    int t = threadIdx.x;
    int l = t & 63, wv = t >> 6;
    int i0 = blockIdx.x, bh = blockIdx.y;

    if (t < 16) {
        int row = i0 * 16 + t;
        f32x4 m4 = *(const f32x4*)(pm + ((size_t)bh * SS + row) * 4);
        f32x4 l4 = *(const f32x4*)(pl + ((size_t)bh * SS + row) * 4);
        float M = fmaxf(fmaxf(m4[0], m4[1]), fmaxf(m4[2], m4[3]));
        float e0 = __expf(m4[0] - M), e1 = __expf(m4[1] - M);
        float e2 = __expf(m4[2] - M), e3 = __expf(m4[3] - M);
        float L = l4[0] * e0 + l4[1] * e1 + l4[2] * e2 + l4[3] * e3;
        float inv = 1.f / L;
        scl[0][t] = e0 * inv; scl[1][t] = e1 * inv;
        scl[2][t] = e2 * inv; scl[3][t] = e3 * inv;
    }
    __syncthreads();

    const __bf16* pbase = pws + ((size_t)bh * SS + i0 * 16) * SS;
    float* abase = attn + ((size_t)bh * SS + i0 * 16) * SS;

    // ---- phase C: final attn write (nontemporal, never re-read) ----
    int colq = l >> 4;   // 8 cols per lane stay within one j-quarter
#pragma unroll
    for (int rr = 0; rr < 4; ++rr) {
        int row = wv * 4 + rr;
        bf16x8 p = *(const bf16x8*)(pbase + (size_t)row * SS + l * 8);
        float s = scl[colq][row];
        f32x4 o0, o1;
        o0[0] = (float)p[0] * s; o0[1] = (float)p[1] * s;
        o0[2] = (float)p[2] * s; o0[3] = (float)p[3] * s;
        o1[0] = (float)p[4] * s; o1[1] = (float)p[5] * s;
        o1[2] = (float)p[6] * s; o1[3] = (float)p[7] * s;
        __builtin_nontemporal_store(o0, (f32x4*)(abase + (size_t)row * SS + l * 8));
        __builtin_nontemporal_store(o1, (f32x4*)(abase + (size_t)row * SS + l * 8 + 4));
    }

    // ---- phase B: PV with per-quarter accumulators ----
    int m = l & 15, quad = l >> 4;
    const __bf16* prow = pbase + (size_t)m * SS + quad * 8;
    const __bf16* vrow = Vt + ((size_t)bh * DK + wv * 16 + m) * SS + quad * 8;
    float ctxv[4] = {0.f, 0.f, 0.f, 0.f};
#pragma unroll
    for (int q = 0; q < 4; ++q) {
        f32x4 acc = {0.f, 0.f, 0.f, 0.f};
#pragma unroll
        for (int kk = 0; kk < 4; ++kk) {
            int k0 = q * 128 + kk * 32;
            bf16x8 aF = *(const bf16x8*)(prow + k0);
            bf16x8 bF = *(const bf16x8*)(vrow + k0);
            acc = __builtin_amdgcn_mfma_f32_16x16x32_bf16(aF, bF, acc, 0, 0, 0);
        }
#pragma unroll
        for (int r = 0; r < 4; ++r) ctxv[r] += acc[r] * scl[q][quad * 4 + r];
    }
    int b = bh >> 3, h = bh & 7;
#pragma unroll
    for (int r = 0; r < 4; ++r) {
        ctx_bsd[((size_t)(b * SS + i0 * 16 + quad * 4 + r)) * DD + h * DK + wv * 16 + m]
            = (__bf16)ctxv[r];
    }
}

// ---------------- fused: x = ctx @ Wo^T + bo + query, then LayerNorm -> y ----------
// grid (tm=128), block (64,8). wave w owns 64 output cols; LN over the 16-row
// tile staged in LDS (pad 516 floats -> 2-way max bank alias on b32 writes).
__launch_bounds__(512, 2)
__global__ void outln_kernel(const __bf16* __restrict__ Xc, const __bf16* __restrict__ Wobf,
                             const float* __restrict__ bo, const float* __restrict__ query,
                             const float* __restrict__ gamma, const float* __restrict__ beta,
                             float* __restrict__ y) {
    __shared__ float xsh[16 * 516];

    int lane = threadIdx.x, w = threadIdx.y;
    int tm = blockIdx.x;
    int m = lane & 15, quad = lane >> 4;

    const __bf16* arow = Xc + (size_t)(tm * 16 + m) * DD + quad * 8;

    f32x4 acc[4] = {{0.f,0.f,0.f,0.f},{0.f,0.f,0.f,0.f},{0.f,0.f,0.f,0.f},{0.f,0.f,0.f,0.f}};
    for (int k0 = 0; k0 < DD; k0 += 32) {
        bf16x8 a = *(const bf16x8*)(arow + k0);
#pragma unroll
        for (int tile = 0; tile < 4; ++tile) {
            const __bf16* brow = Wobf + (size_t)(w * 64 + tile * 16 + m) * DD + k0 + quad * 8;
            bf16x8 b = *(const bf16x8*)brow;
            acc[tile] = __builtin_amdgcn_mfma_f32_16x16x32_bf16(a, b, acc[tile], 0, 0, 0);
        }
    }

#pragma unroll
    for (int tile = 0; tile < 4; ++tile) {
        int col = w * 64 + tile * 16 + m;
        float bv = bo[col];
#pragma unroll
        for (int r = 0; r < 4; ++r) {
            int row = quad * 4 + r;
            int rowg = tm * 16 + row;
            xsh[row * 516 + col] = acc[tile][r] + bv + query[(size_t)rowg * DD + col];
        }
    }
    __syncthreads();

    // LN: wave w -> rows 2w, 2w+1; lane covers 8 cols
#pragma unroll
    for (int rr = 0; rr < 2; ++rr) {
        int row = w * 2 + rr;
        const float* xr = &xsh[row * 516];
        f32x4 xa = *(const f32x4*)(xr + lane * 8);
        f32x4 xb = *(const f32x4*)(xr + lane * 8 + 4);
        float s  = xa[0] + xa[1] + xa[2] + xa[3] + xb[0] + xb[1] + xb[2] + xb[3];
        float sq = xa[0]*xa[0] + xa[1]*xa[1] + xa[2]*xa[2] + xa[3]*xa[3]
                 + xb[0]*xb[0] + xb[1]*xb[1] + xb[2]*xb[2] + xb[3]*xb[3];
#pragma unroll
        for (int off = 32; off >= 1; off >>= 1) {
            s  += __shfl_xor(s, off);
            sq += __shfl_xor(sq, off);
        }
        float mu = s * (1.f / DD);
        float var = sq * (1.f / DD) - mu * mu;
        float inv = rsqrtf(var + 1e-5f);
        f32x4 g0 = *(const f32x4*)(gamma + lane * 8);
        f32x4 g1 = *(const f32x4*)(gamma + lane * 8 + 4);
        f32x4 b0 = *(const f32x4*)(beta + lane * 8);
        f32x4 b1 = *(const f32x4*)(beta + lane * 8 + 4);
        f32x4 o0, o1;
#pragma unroll
        for (int e = 0; e < 4; ++e) {
            o0[e] = (xa[e] - mu) * inv * g0[e] + b0[e];
            o1[e] = (xb[e] - mu) * inv * g1[e] + b1[e];
        }
        float* yr = y + (size_t)(tm * 16 + row) * DD + lane * 8;
        *(f32x4*)yr = o0;
        *(f32x4*)(yr + 4) = o1;
    }
}

extern "C" void kernel_launch(void* const* d_in, const int* in_sizes, int n_in,
                              void* d_out, int out_size, void* d_ws, size_t ws_size,
                              hipStream_t stream) {
    const float* query  = (const float*)d_in[0];
    const float* key    = (const float*)d_in[1];
    const float* value  = (const float*)d_in[2];
    const float* Wq     = (const float*)d_in[3];
    const float* bq     = (const float*)d_in[4];
    const float* Wk     = (const float*)d_in[5];
    const float* bk     = (const float*)d_in[6];
    const float* Wv     = (const float*)d_in[7];
    const float* bv     = (const float*)d_in[8];
    const float* Wo     = (const float*)d_in[9];
    const float* bo     = (const float*)d_in[10];
    const float* rtab   = (const float*)d_in[11];
    const float* gamma  = (const float*)d_in[12];
    const float* beta   = (const float*)d_in[13];
    const int*   mask   = (const int*)d_in[14];
    const int*   relpos = (const int*)d_in[15];

    float* out = (float*)d_out;
    float* y    = out;
    float* attn = out + (size_t)BB * SS * DD;

    char* wsb = (char*)d_ws;
    float*  Tm    = (float*)wsb;   wsb += 256;
    __bf16* Qbf   = (__bf16*)wsb;  wsb += (size_t)BB * HH * SS * DK * 2;
    __bf16* Kbf   = (__bf16*)wsb;  wsb += (size_t)BB * HH * SS * DK * 2;
    __bf16* Vtbf  = (__bf16*)wsb;  wsb += (size_t)BB * HH * DK * SS * 2;
    __bf16* ctxbf = (__bf16*)wsb;  wsb += (size_t)BB * SS * DD * 2;
    __bf16* Wobf  = (__bf16*)wsb;  wsb += (size_t)DD * DD * 2;
    __bf16* pws   = (__bf16*)wsb;  wsb += (size_t)BB * HH * SS * SS * 2;
    float*  pm    = (float*)wsb;   wsb += (size_t)BB * HH * SS * 4 * 4;
    float*  pl    = (float*)wsb;   wsb += (size_t)BB * HH * SS * 4 * 4;

    hipLaunchKernelGGL(prep_kernel, dim3(1 + (DD * DD) / (256 * 8)), dim3(256), 0, stream,
                       rtab, Tm, Wo, Wobf);

    dim3 wblk(64, 4);
    hipLaunchKernelGGL(proj_mfma_kernel, dim3(DD / 16, (BB * SS) / 64, 3), wblk, 0, stream,
                       query, key, value, Wq, Wk, Wv, bq, bk, bv, Qbf, Kbf, Vtbf);

    hipLaunchKernelGGL(f1_kernel, dim3(4, SS / 16, BB), dim3(64, 8), 0, stream,
                       Qbf, Kbf, relpos, Tm, mask, pws, pm, pl);

    hipLaunchKernelGGL(f2_kernel, dim3(SS / 16, BB * HH), dim3(256), 0, stream,
                       pws, pm, pl, Vtbf, attn, ctxbf);

    hipLaunchKernelGGL(outln_kernel, dim3((BB * SS) / 16), dim3(64, 8), 0, stream,
                       ctxbf, Wobf, bo, query, gamma, beta, y);
}

// Round 3
// 473.174 us; speedup vs baseline: 1.1433x; 1.1409x over previous
//
#include <hip/hip_runtime.h>
#include <hip/hip_bf16.h>

#define BB 4
#define SS 512
#define DD 512
#define HH 8
#define DK 64
#define PP 16
#define TSZ 33   // 2P+1

typedef __bf16 bf16x8 __attribute__((ext_vector_type(8)));
typedef __bf16 bf16x4 __attribute__((ext_vector_type(4)));
typedef float  f32x4  __attribute__((ext_vector_type(4)));
typedef int    i32x4  __attribute__((ext_vector_type(4)));

union U8 { bf16x8 v; int u[4]; };

__device__ inline bf16x8 cvt8(const float* __restrict__ p) {
    f32x4 a = *(const f32x4*)p;
    f32x4 b = *(const f32x4*)(p + 4);
    bf16x8 r;
    r[0] = (__bf16)a[0]; r[1] = (__bf16)a[1]; r[2] = (__bf16)a[2]; r[3] = (__bf16)a[3];
    r[4] = (__bf16)b[0]; r[5] = (__bf16)b[1]; r[6] = (__bf16)b[2]; r[7] = (__bf16)b[3];
    return r;
}

// ---------------- prep: table mean + ALL f32->bf16 conversions ----------------
// block 0: Tm. blocks 1..2048: one bf16x8 per thread over the concatenation
// {Wq,Wk,Wv,Wo | q,k,v} (524288 vec8 elements total).
__global__ void prep_kernel(const float* __restrict__ rel_table, float* __restrict__ Tm,
                            const float* __restrict__ Wq, const float* __restrict__ Wk,
                            const float* __restrict__ Wv, const float* __restrict__ Wo,
                            const float* __restrict__ q, const float* __restrict__ k,
                            const float* __restrict__ v,
                            __bf16* __restrict__ Wqb, __bf16* __restrict__ Wkb,
                            __bf16* __restrict__ Wvb, __bf16* __restrict__ Wob,
                            __bf16* __restrict__ qb, __bf16* __restrict__ kb,
                            __bf16* __restrict__ vb) {
    int bid = blockIdx.x, t = threadIdx.x;
    if (bid == 0) {
        if (t < TSZ) {
            float s = 0.f;
            for (int e = 0; e < DK; ++e) s += rel_table[t * DK + e];
            Tm[t] = s * (1.f / DK);
        }
        return;
    }
    int idx = (bid - 1) * 256 + t;           // vec8 index, exactly 524288 threads
    const float* s; __bf16* d; int off;
    if (idx < 131072) {                       // 4 weight matrices, 32768 vec8 each
        int w = idx >> 15; off = idx & 32767;
        s = (w == 0) ? Wq : (w == 1) ? Wk : (w == 2) ? Wv : Wo;
        d = (w == 0) ? Wqb : (w == 1) ? Wkb : (w == 2) ? Wvb : Wob;
    } else if (idx < 262144) { s = q; d = qb; off = idx - 131072; }
    else if (idx < 393216)   { s = k; d = kb; off = idx - 262144; }
    else                     { s = v; d = vb; off = idx - 393216; }
    *(bf16x8*)(d + (size_t)off * 8) = cvt8(s + (size_t)off * 8);
}

// ---------------- QKV projection, pure-bf16 MFMA, 4 n-tiles per wave ----------------
// grid (DD/64, (BB*SS)/64, 3), block (64,4). wave w: rows tm*16..+15, cols bx*64..+63.
__global__ void proj_mfma_kernel(const __bf16* __restrict__ X0, const __bf16* __restrict__ X1,
                                 const __bf16* __restrict__ X2,
                                 const __bf16* __restrict__ W0, const __bf16* __restrict__ W1,
                                 const __bf16* __restrict__ W2,
                                 const float* __restrict__ B0, const float* __restrict__ B1,
                                 const float* __restrict__ B2,
                                 __bf16* __restrict__ O0, __bf16* __restrict__ O1,
                                 __bf16* __restrict__ O2) {
    int z = blockIdx.z;
    const __bf16* X = (z == 0) ? X0 : (z == 1) ? X1 : X2;
    const __bf16* W = (z == 0) ? W0 : (z == 1) ? W1 : W2;
    const float* bias = (z == 0) ? B0 : (z == 1) ? B1 : B2;
    __bf16* out = (z == 0) ? O0 : (z == 1) ? O1 : O2;
    int mode = (z == 2);

    int lane = threadIdx.x, wave = threadIdx.y;
    int tm = blockIdx.y * 4 + wave;
    int tn0 = blockIdx.x * 4;
    int m = lane & 15, quad = lane >> 4;

    const __bf16* arow = X + (size_t)(tm * 16 + m) * DD + quad * 8;

    f32x4 acc[4] = {{0.f,0.f,0.f,0.f},{0.f,0.f,0.f,0.f},{0.f,0.f,0.f,0.f},{0.f,0.f,0.f,0.f}};
    for (int k0 = 0; k0 < DD; k0 += 32) {
        bf16x8 a = *(const bf16x8*)(arow + k0);
#pragma unroll
        for (int tt = 0; tt < 4; ++tt) {
            const __bf16* brow = W + (size_t)((tn0 + tt) * 16 + m) * DD + k0 + quad * 8;
            bf16x8 b = *(const bf16x8*)brow;
            acc[tt] = __builtin_amdgcn_mfma_f32_16x16x32_bf16(a, b, acc[tt], 0, 0, 0);
        }
    }

#pragma unroll
    for (int tt = 0; tt < 4; ++tt) {
        int col = (tn0 + tt) * 16 + m;
        int h = col >> 6, dk = col & (DK - 1);
        float bv = bias[col];
#pragma unroll
        for (int r = 0; r < 4; ++r) {
            int rowg = tm * 16 + quad * 4 + r;
            int b = rowg >> 9, i = rowg & (SS - 1);
            float vv = acc[tt][r] + bv;
            if (mode == 0)
                out[((size_t)(b * HH + h) * SS + i) * DK + dk] = (__bf16)vv;
            else
                out[((size_t)(b * HH + h) * DK + dk) * SS + i] = (__bf16)vv;
        }
    }
}

// ---------------- F1: scores + relbias(MFMA, reg-gather) + partial softmax ----------
// grid (jq=4, i0=32, b=4), block (64,8). wave w: head w for scores/softmax,
// j-tile w for bias. ONE barrier. p' stored bf16. relpos loads nontemporal.
__launch_bounds__(512, 4)
__global__ void f1_kernel(const __bf16* __restrict__ Qbf, const __bf16* __restrict__ Kbf,
                          const int* __restrict__ relpos, const float* __restrict__ Tm,
                          const int* __restrict__ mask, __bf16* __restrict__ pws,
                          float* __restrict__ pm, float* __restrict__ pl) {
    // bias_sh[h][i][j_local]: strides h:2112, i:132 (pad -> max 2-way bank alias)
    __shared__ float bias_sh[8 * 16 * 132];

    int l = threadIdx.x, w = threadIdx.y;
    int jq = blockIdx.x, i0 = blockIdx.y, b = blockIdx.z;
    int m = l & 15, quad = l >> 4;

    // Tmean as bf16 bits, register-resident (lanes 0..32)
    float tmf = Tm[l < TSZ ? l : 0];
    int tmb = (int)__builtin_bit_cast(unsigned short, (__bf16)tmf);

    // ---- bias phase: wave w handles local j-tile w, all h, i = 0..15 ----
    {
        const int ISTR = SS * DK; // 32768
        const int* rbase = relpos + ((size_t)(b * SS + i0 * 16) * SS + jq * 128 + w * 16 + m) * DK + quad * 8;
        // depth-2 prefetch of relpos (HBM latency ~900cy), nontemporal (stream-once)
        i32x4 u0 = __builtin_nontemporal_load((const i32x4*)(rbase));
        i32x4 u1 = __builtin_nontemporal_load((const i32x4*)(rbase + 4));
        i32x4 u2 = __builtin_nontemporal_load((const i32x4*)(rbase + 32));
        i32x4 u3 = __builtin_nontemporal_load((const i32x4*)(rbase + 36));
        const int* pb1 = rbase + ISTR;
        i32x4 v0 = __builtin_nontemporal_load((const i32x4*)(pb1));
        i32x4 v1 = __builtin_nontemporal_load((const i32x4*)(pb1 + 4));
        i32x4 v2 = __builtin_nontemporal_load((const i32x4*)(pb1 + 32));
        i32x4 v3 = __builtin_nontemporal_load((const i32x4*)(pb1 + 36));
        for (int i = 0; i < 16; ++i) {
            i32x4 n0, n1, n2, n3;
            if (i < 14) {
                const int* nb = rbase + (i + 2) * ISTR;
                n0 = __builtin_nontemporal_load((const i32x4*)(nb));
                n1 = __builtin_nontemporal_load((const i32x4*)(nb + 4));
                n2 = __builtin_nontemporal_load((const i32x4*)(nb + 32));
                n3 = __builtin_nontemporal_load((const i32x4*)(nb + 36));
            }
            // A-frags: Q[h=m&7, i, d]
            const __bf16* qp = Qbf + ((size_t)(b * HH + (m & 7)) * SS + i0 * 16 + i) * DK + quad * 8;
            bf16x8 A0 = *(const bf16x8*)qp;
            bf16x8 A1 = *(const bf16x8*)(qp + 32);
            // B-frags: Tm[clip(idx)] via bpermute LUT
#define LUT(vv) __builtin_amdgcn_ds_bpermute((min(max((vv), -PP), PP) + PP) << 2, tmb)
            U8 Bf0, Bf1;
            Bf0.u[0] = LUT(u0[0]) | (LUT(u0[1]) << 16);
            Bf0.u[1] = LUT(u0[2]) | (LUT(u0[3]) << 16);
            Bf0.u[2] = LUT(u1[0]) | (LUT(u1[1]) << 16);
            Bf0.u[3] = LUT(u1[2]) | (LUT(u1[3]) << 16);
            Bf1.u[0] = LUT(u2[0]) | (LUT(u2[1]) << 16);
            Bf1.u[1] = LUT(u2[2]) | (LUT(u2[3]) << 16);
            Bf1.u[2] = LUT(u3[0]) | (LUT(u3[1]) << 16);
            Bf1.u[3] = LUT(u3[2]) | (LUT(u3[3]) << 16);
#undef LUT
            f32x4 accB = {0.f, 0.f, 0.f, 0.f};
            accB = __builtin_amdgcn_mfma_f32_16x16x32_bf16(A0, Bf0.v, accB, 0, 0, 0);
            accB = __builtin_amdgcn_mfma_f32_16x16x32_bf16(A1, Bf1.v, accB, 0, 0, 0);
            if (quad < 2) {
#pragma unroll
                for (int r = 0; r < 4; ++r) {
                    int h = quad * 4 + r;   // 0..7
                    bias_sh[h * 2112 + i * 132 + w * 16 + m] = accB[r];
                }
            }
            u0 = v0; u1 = v1; u2 = v2; u3 = v3;
            v0 = n0; v1 = n1; v2 = n2; v3 = n3;
        }
    }

    // ---- score phase: wave w = head w ----
    const __bf16* qrow = Qbf + ((size_t)(b * HH + w) * SS + i0 * 16 + m) * DK + quad * 8;
    bf16x8 a0 = *(const bf16x8*)qrow;
    bf16x8 a1 = *(const bf16x8*)(qrow + 32);

    f32x4 acc[8];
#pragma unroll
    for (int jt = 0; jt < 8; ++jt) {
        const __bf16* krow = Kbf + ((size_t)(b * HH + w) * SS + jq * 128 + jt * 16 + m) * DK + quad * 8;
        bf16x8 b0 = *(const bf16x8*)krow;
        bf16x8 b1 = *(const bf16x8*)(krow + 32);
        f32x4 c = {0.f, 0.f, 0.f, 0.f};
        c = __builtin_amdgcn_mfma_f32_16x16x32_bf16(a0, b0, c, 0, 0, 0);
        c = __builtin_amdgcn_mfma_f32_16x16x32_bf16(a1, b1, c, 0, 0, 0);
        acc[jt] = c;
    }

    __syncthreads();   // bias_sh ready

    // ---- combine: scale + bias ----
#pragma unroll
    for (int jt = 0; jt < 8; ++jt) {
#pragma unroll
        for (int r = 0; r < 4; ++r) {
            float bv = bias_sh[w * 2112 + (quad * 4 + r) * 132 + jt * 16 + m];
            acc[jt][r] = acc[jt][r] * 0.125f + bv;
        }
    }

    // ---- mask ----
#pragma unroll
    for (int jt = 0; jt < 8; ++jt) {
        int mv = mask[b * SS + jq * 128 + jt * 16 + m];
        if (mv == 0) {
#pragma unroll
            for (int r = 0; r < 4; ++r) acc[jt][r] = -1e9f;
        }
    }

    // ---- partial softmax over this quarter ----
#pragma unroll
    for (int r = 0; r < 4; ++r) {
        float mx = -1e30f;
#pragma unroll
        for (int jt = 0; jt < 8; ++jt) mx = fmaxf(mx, acc[jt][r]);
        mx = fmaxf(mx, __shfl_xor(mx, 1));
        mx = fmaxf(mx, __shfl_xor(mx, 2));
        mx = fmaxf(mx, __shfl_xor(mx, 4));
        mx = fmaxf(mx, __shfl_xor(mx, 8));
        float sum = 0.f;
#pragma unroll
        for (int jt = 0; jt < 8; ++jt) {
            float e = __expf(acc[jt][r] - mx);
            acc[jt][r] = e;
            sum += e;
        }
        sum += __shfl_xor(sum, 1);
        sum += __shfl_xor(sum, 2);
        sum += __shfl_xor(sum, 4);
        sum += __shfl_xor(sum, 8);
        if (m == 0) {
            int row = i0 * 16 + quad * 4 + r;
            pm[((size_t)(b * HH + w) * SS + row) * 4 + jq] = mx;
            pl[((size_t)(b * HH + w) * SS + row) * 4 + jq] = sum;
        }
    }

    // ---- store p' (unnormalized, bf16) ----
#pragma unroll
    for (int jt = 0; jt < 8; ++jt) {
#pragma unroll
        for (int r = 0; r < 4; ++r) {
            pws[((size_t)(b * HH + w) * SS + i0 * 16 + quad * 4 + r) * SS
                + jq * 128 + jt * 16 + m] = (__bf16)acc[jt][r];
        }
    }
}

// ---------------- F2: attn = scl*p' (f32 out) + ctx = P @ V, no LDS staging --------
__launch_bounds__(256, 4)
__global__ void f2_kernel(const __bf16* __restrict__ pws, const float* __restrict__ pm,
                          const float* __restrict__ pl, const __bf16* __restrict__ Vt,
                          float* __restrict__ attn, __bf16* __restrict__ ctx_bsd) {
    __shared__ float scl[4][16];

    int t = threadIdx.x;
    int l = t & 63, wv = t >> 6;
    int i0 = blockIdx.x, bh = blockIdx.y;

    if (t < 16) {
        int row = i0 * 16 + t;
        f32x4 m4 = *(const f32x4*)(pm + ((size_t)bh * SS + row) * 4);
        f32x4 l4 = *(const f32x4*)(pl + ((size_t)bh * SS + row) * 4);
        float M = fmaxf(fmaxf(m4[0], m4[1]), fmaxf(m4[2], m4[3]));
        float e0 = __expf(m4[0] - M), e1 = __expf(m4[1] - M);
        float e2 = __expf(m4[2] - M), e3 = __expf(m4[3] - M);
        float L = l4[0] * e0 + l4[1] * e1 + l4[2] * e2 + l4[3] * e3;
        float inv = 1.f / L;
        scl[0][t] = e0 * inv; scl[1][t] = e1 * inv;
        scl[2][t] = e2 * inv; scl[3][t] = e3 * inv;
    }
    __syncthreads();

    const __bf16* pbase = pws + ((size_t)bh * SS + i0 * 16) * SS;
    float* abase = attn + ((size_t)bh * SS + i0 * 16) * SS;

    // ---- phase C: final attn write (nontemporal, never re-read) ----
    int colq = l >> 4;   // 8 cols per lane stay within one j-quarter
#pragma unroll
    for (int rr = 0; rr < 4; ++rr) {
        int row = wv * 4 + rr;
        bf16x8 p = *(const bf16x8*)(pbase + (size_t)row * SS + l * 8);
        float s = scl[colq][row];
        f32x4 o0, o1;
        o0[0] = (float)p[0] * s; o0[1] = (float)p[1] * s;
        o0[2] = (float)p[2] * s; o0[3] = (float)p[3] * s;
        o1[0] = (float)p[4] * s; o1[1] = (float)p[5] * s;
        o1[2] = (float)p[6] * s; o1[3] = (float)p[7] * s;
        __builtin_nontemporal_store(o0, (f32x4*)(abase + (size_t)row * SS + l * 8));
        __builtin_nontemporal_store(o1, (f32x4*)(abase + (size_t)row * SS + l * 8 + 4));
    }

    // ---- phase B: PV with per-quarter accumulators ----
    int m = l & 15, quad = l >> 4;
    const __bf16* prow = pbase + (size_t)m * SS + quad * 8;
    const __bf16* vrow = Vt + ((size_t)bh * DK + wv * 16 + m) * SS + quad * 8;
    float ctxv[4] = {0.f, 0.f, 0.f, 0.f};
#pragma unroll
    for (int q = 0; q < 4; ++q) {
        f32x4 acc = {0.f, 0.f, 0.f, 0.f};
#pragma unroll
        for (int kk = 0; kk < 4; ++kk) {
            int k0 = q * 128 + kk * 32;
            bf16x8 aF = *(const bf16x8*)(prow + k0);
            bf16x8 bF = *(const bf16x8*)(vrow + k0);
            acc = __builtin_amdgcn_mfma_f32_16x16x32_bf16(aF, bF, acc, 0, 0, 0);
        }
#pragma unroll
        for (int r = 0; r < 4; ++r) ctxv[r] += acc[r] * scl[q][quad * 4 + r];
    }
    int b = bh >> 3, h = bh & 7;
#pragma unroll
    for (int r = 0; r < 4; ++r) {
        ctx_bsd[((size_t)(b * SS + i0 * 16 + quad * 4 + r)) * DD + h * DK + wv * 16 + m]
            = (__bf16)ctxv[r];
    }
}

// ---------------- fused: x = ctx @ Wo^T + bo + query, then LayerNorm -> y ----------
__launch_bounds__(512, 2)
__global__ void outln_kernel(const __bf16* __restrict__ Xc, const __bf16* __restrict__ Wobf,
                             const float* __restrict__ bo, const float* __restrict__ query,
                             const float* __restrict__ gamma, const float* __restrict__ beta,
                             float* __restrict__ y) {
    __shared__ float xsh[16 * 516];

    int lane = threadIdx.x, w = threadIdx.y;
    int tm = blockIdx.x;
    int m = lane & 15, quad = lane >> 4;

    const __bf16* arow = Xc + (size_t)(tm * 16 + m) * DD + quad * 8;

    f32x4 acc[4] = {{0.f,0.f,0.f,0.f},{0.f,0.f,0.f,0.f},{0.f,0.f,0.f,0.f},{0.f,0.f,0.f,0.f}};
    for (int k0 = 0; k0 < DD; k0 += 32) {
        bf16x8 a = *(const bf16x8*)(arow + k0);
#pragma unroll
        for (int tile = 0; tile < 4; ++tile) {
            const __bf16* brow = Wobf + (size_t)(w * 64 + tile * 16 + m) * DD + k0 + quad * 8;
            bf16x8 b = *(const bf16x8*)brow;
            acc[tile] = __builtin_amdgcn_mfma_f32_16x16x32_bf16(a, b, acc[tile], 0, 0, 0);
        }
    }

#pragma unroll
    for (int tile = 0; tile < 4; ++tile) {
        int col = w * 64 + tile * 16 + m;
        float bv = bo[col];
#pragma unroll
        for (int r = 0; r < 4; ++r) {
            int row = quad * 4 + r;
            int rowg = tm * 16 + row;
            xsh[row * 516 + col] = acc[tile][r] + bv + query[(size_t)rowg * DD + col];
        }
    }
    __syncthreads();

    // LN: wave w -> rows 2w, 2w+1; lane covers 8 cols
#pragma unroll
    for (int rr = 0; rr < 2; ++rr) {
        int row = w * 2 + rr;
        const float* xr = &xsh[row * 516];
        f32x4 xa = *(const f32x4*)(xr + lane * 8);
        f32x4 xb = *(const f32x4*)(xr + lane * 8 + 4);
        float s  = xa[0] + xa[1] + xa[2] + xa[3] + xb[0] + xb[1] + xb[2] + xb[3];
        float sq = xa[0]*xa[0] + xa[1]*xa[1] + xa[2]*xa[2] + xa[3]*xa[3]
                 + xb[0]*xb[0] + xb[1]*xb[1] + xb[2]*xb[2] + xb[3]*xb[3];
#pragma unroll
        for (int off = 32; off >= 1; off >>= 1) {
            s  += __shfl_xor(s, off);
            sq += __shfl_xor(sq, off);
        }
        float mu = s * (1.f / DD);
        float var = sq * (1.f / DD) - mu * mu;
        float inv = rsqrtf(var + 1e-5f);
        f32x4 g0 = *(const f32x4*)(gamma + lane * 8);
        f32x4 g1 = *(const f32x4*)(gamma + lane * 8 + 4);
        f32x4 b0 = *(const f32x4*)(beta + lane * 8);
        f32x4 b1 = *(const f32x4*)(beta + lane * 8 + 4);
        f32x4 o0, o1;
#pragma unroll
        for (int e = 0; e < 4; ++e) {
            o0[e] = (xa[e] - mu) * inv * g0[e] + b0[e];
            o1[e] = (xb[e] - mu) * inv * g1[e] + b1[e];
        }
        float* yr = y + (size_t)(tm * 16 + row) * DD + lane * 8;
        *(f32x4*)yr = o0;
        *(f32x4*)(yr + 4) = o1;
    }
}

extern "C" void kernel_launch(void* const* d_in, const int* in_sizes, int n_in,
                              void* d_out, int out_size, void* d_ws, size_t ws_size,
                              hipStream_t stream) {
    const float* query  = (const float*)d_in[0];
    const float* key    = (const float*)d_in[1];
    const float* value  = (const float*)d_in[2];
    const float* Wq     = (const float*)d_in[3];
    const float* bq     = (const float*)d_in[4];
    const float* Wk     = (const float*)d_in[5];
    const float* bk     = (const float*)d_in[6];
    const float* Wv     = (const float*)d_in[7];
    const float* bv     = (const float*)d_in[8];
    const float* Wo     = (const float*)d_in[9];
    const float* bo     = (const float*)d_in[10];
    const float* rtab   = (const float*)d_in[11];
    const float* gamma  = (const float*)d_in[12];
    const float* beta   = (const float*)d_in[13];
    const int*   mask   = (const int*)d_in[14];
    const int*   relpos = (const int*)d_in[15];

    float* out = (float*)d_out;
    float* y    = out;
    float* attn = out + (size_t)BB * SS * DD;

    char* wsb = (char*)d_ws;
    float*  Tm    = (float*)wsb;   wsb += 256;
    __bf16* Qbf   = (__bf16*)wsb;  wsb += (size_t)BB * HH * SS * DK * 2;
    __bf16* Kbf   = (__bf16*)wsb;  wsb += (size_t)BB * HH * SS * DK * 2;
    __bf16* Vtbf  = (__bf16*)wsb;  wsb += (size_t)BB * HH * DK * SS * 2;
    __bf16* ctxbf = (__bf16*)wsb;  wsb += (size_t)BB * SS * DD * 2;
    __bf16* Wqb   = (__bf16*)wsb;  wsb += (size_t)DD * DD * 2;
    __bf16* Wkb   = (__bf16*)wsb;  wsb += (size_t)DD * DD * 2;
    __bf16* Wvb   = (__bf16*)wsb;  wsb += (size_t)DD * DD * 2;
    __bf16* Wob   = (__bf16*)wsb;  wsb += (size_t)DD * DD * 2;
    __bf16* qb    = (__bf16*)wsb;  wsb += (size_t)BB * SS * DD * 2;
    __bf16* kb    = (__bf16*)wsb;  wsb += (size_t)BB * SS * DD * 2;
    __bf16* vb    = (__bf16*)wsb;  wsb += (size_t)BB * SS * DD * 2;
    __bf16* pws   = (__bf16*)wsb;  wsb += (size_t)BB * HH * SS * SS * 2;
    float*  pm    = (float*)wsb;   wsb += (size_t)BB * HH * SS * 4 * 4;
    float*  pl    = (float*)wsb;   wsb += (size_t)BB * HH * SS * 4 * 4;

    hipLaunchKernelGGL(prep_kernel, dim3(2049), dim3(256), 0, stream,
                       rtab, Tm, Wq, Wk, Wv, Wo, query, key, value,
                       Wqb, Wkb, Wvb, Wob, qb, kb, vb);

    hipLaunchKernelGGL(proj_mfma_kernel, dim3(DD / 64, (BB * SS) / 64, 3), dim3(64, 4), 0, stream,
                       qb, kb, vb, Wqb, Wkb, Wvb, bq, bk, bv, Qbf, Kbf, Vtbf);

    hipLaunchKernelGGL(f1_kernel, dim3(4, SS / 16, BB), dim3(64, 8), 0, stream,
                       Qbf, Kbf, relpos, Tm, mask, pws, pm, pl);

    hipLaunchKernelGGL(f2_kernel, dim3(SS / 16, BB * HH), dim3(256), 0, stream,
                       pws, pm, pl, Vtbf, attn, ctxbf);

    hipLaunchKernelGGL(outln_kernel, dim3((BB * SS) / 16), dim3(64, 8), 0, stream,
                       ctxbf, Wob, bo, query, gamma, beta, y);
}

// Round 4
// 465.292 us; speedup vs baseline: 1.1627x; 1.0169x over previous
//
#include <hip/hip_runtime.h>
#include <hip/hip_bf16.h>

#define BB 4
#define SS 512
#define DD 512
#define HH 8
#define DK 64
#define PP 16
#define TSZ 33   // 2P+1

typedef __bf16 bf16x8 __attribute__((ext_vector_type(8)));
typedef __bf16 bf16x4 __attribute__((ext_vector_type(4)));
typedef float  f32x4  __attribute__((ext_vector_type(4)));
typedef int    i32x4  __attribute__((ext_vector_type(4)));

union U8 { bf16x8 v; int u[4]; };

__device__ inline bf16x8 cvt8(const float* __restrict__ p) {
    f32x4 a = *(const f32x4*)p;
    f32x4 b = *(const f32x4*)(p + 4);
    bf16x8 r;
    r[0] = (__bf16)a[0]; r[1] = (__bf16)a[1]; r[2] = (__bf16)a[2]; r[3] = (__bf16)a[3];
    r[4] = (__bf16)b[0]; r[5] = (__bf16)b[1]; r[6] = (__bf16)b[2]; r[7] = (__bf16)b[3];
    return r;
}

// ---------------- prep: table mean + ALL f32->bf16 conversions ----------------
__global__ void prep_kernel(const float* __restrict__ rel_table, float* __restrict__ Tm,
                            const float* __restrict__ Wq, const float* __restrict__ Wk,
                            const float* __restrict__ Wv, const float* __restrict__ Wo,
                            const float* __restrict__ q, const float* __restrict__ k,
                            const float* __restrict__ v,
                            __bf16* __restrict__ Wqb, __bf16* __restrict__ Wkb,
                            __bf16* __restrict__ Wvb, __bf16* __restrict__ Wob,
                            __bf16* __restrict__ qb, __bf16* __restrict__ kb,
                            __bf16* __restrict__ vb) {
    int bid = blockIdx.x, t = threadIdx.x;
    if (bid == 0) {
        if (t < TSZ) {
            float s = 0.f;
            for (int e = 0; e < DK; ++e) s += rel_table[t * DK + e];
            Tm[t] = s * (1.f / DK);
        }
        return;
    }
    int idx = (bid - 1) * 256 + t;           // vec8 index, exactly 524288 threads
    const float* s; __bf16* d; int off;
    if (idx < 131072) {                       // 4 weight matrices, 32768 vec8 each
        int w = idx >> 15; off = idx & 32767;
        s = (w == 0) ? Wq : (w == 1) ? Wk : (w == 2) ? Wv : Wo;
        d = (w == 0) ? Wqb : (w == 1) ? Wkb : (w == 2) ? Wvb : Wob;
    } else if (idx < 262144) { s = q; d = qb; off = idx - 131072; }
    else if (idx < 393216)   { s = k; d = kb; off = idx - 262144; }
    else                     { s = v; d = vb; off = idx - 393216; }
    *(bf16x8*)(d + (size_t)off * 8) = cvt8(s + (size_t)off * 8);
}

// ---------------- QKV projection, pure-bf16 MFMA, 4 n-tiles per wave ----------------
__global__ void proj_mfma_kernel(const __bf16* __restrict__ X0, const __bf16* __restrict__ X1,
                                 const __bf16* __restrict__ X2,
                                 const __bf16* __restrict__ W0, const __bf16* __restrict__ W1,
                                 const __bf16* __restrict__ W2,
                                 const float* __restrict__ B0, const float* __restrict__ B1,
                                 const float* __restrict__ B2,
                                 __bf16* __restrict__ O0, __bf16* __restrict__ O1,
                                 __bf16* __restrict__ O2) {
    int z = blockIdx.z;
    const __bf16* X = (z == 0) ? X0 : (z == 1) ? X1 : X2;
    const __bf16* W = (z == 0) ? W0 : (z == 1) ? W1 : W2;
    const float* bias = (z == 0) ? B0 : (z == 1) ? B1 : B2;
    __bf16* out = (z == 0) ? O0 : (z == 1) ? O1 : O2;
    int mode = (z == 2);

    int lane = threadIdx.x, wave = threadIdx.y;
    int tm = blockIdx.y * 4 + wave;
    int tn0 = blockIdx.x * 4;
    int m = lane & 15, quad = lane >> 4;

    const __bf16* arow = X + (size_t)(tm * 16 + m) * DD + quad * 8;

    f32x4 acc[4] = {{0.f,0.f,0.f,0.f},{0.f,0.f,0.f,0.f},{0.f,0.f,0.f,0.f},{0.f,0.f,0.f,0.f}};
    for (int k0 = 0; k0 < DD; k0 += 32) {
        bf16x8 a = *(const bf16x8*)(arow + k0);
#pragma unroll
        for (int tt = 0; tt < 4; ++tt) {
            const __bf16* brow = W + (size_t)((tn0 + tt) * 16 + m) * DD + k0 + quad * 8;
            bf16x8 b = *(const bf16x8*)brow;
            acc[tt] = __builtin_amdgcn_mfma_f32_16x16x32_bf16(a, b, acc[tt], 0, 0, 0);
        }
    }

#pragma unroll
    for (int tt = 0; tt < 4; ++tt) {
        int col = (tn0 + tt) * 16 + m;
        int h = col >> 6, dk = col & (DK - 1);
        float bv = bias[col];
        if (mode == 0) {
#pragma unroll
            for (int r = 0; r < 4; ++r) {
                int rowg = tm * 16 + quad * 4 + r;
                int b = rowg >> 9, i = rowg & (SS - 1);
                out[((size_t)(b * HH + h) * SS + i) * DK + dk] = (__bf16)(acc[tt][r] + bv);
            }
        } else {
            // V^T: rows i = tm*16+quad*4+..+3 are consecutive -> one 8B store
            int rbase = tm * 16 + quad * 4;
            int b = rbase >> 9, i = rbase & (SS - 1);
            bf16x4 pk;
#pragma unroll
            for (int r = 0; r < 4; ++r) pk[r] = (__bf16)(acc[tt][r] + bv);
            *(bf16x4*)(out + ((size_t)(b * HH + h) * DK + dk) * SS + i) = pk;
        }
    }
}

// ---------------- F1: scores + relbias(MFMA, reg-gather) + partial softmax ----------
// grid (jq=4, i0=32, b=4), block (64,8). wave w: head w for scores/softmax,
// j-tile w for bias. Bias-phase Q frags staged in LDS (keeps the vmcnt queue
// pure relpos-prefetch: MFMA waits on lgkmcnt, never drains the prefetches).
__launch_bounds__(512, 4)
__global__ void f1_kernel(const __bf16* __restrict__ Qbf, const __bf16* __restrict__ Kbf,
                          const int* __restrict__ relpos, const float* __restrict__ Tm,
                          const int* __restrict__ mask, __bf16* __restrict__ pws,
                          float* __restrict__ pm, float* __restrict__ pl) {
    // bias_sh[h][i][j_local] bf16: strides h:2112, i:132 (33.8 KB)
    __shared__ __bf16 bias_sh[8 * 16 * 132];
    // Qt[i][qq][h]: bf16x8 fragment Q[h][i0*16+i][qq*8..+7]; reads are
    // conflict-free (bank = h*4+word) and dup lanes broadcast. 16 KB.
    __shared__ bf16x8 Qt[16][8][8];

    int l = threadIdx.x, w = threadIdx.y;
    int jq = blockIdx.x, i0 = blockIdx.y, b = blockIdx.z;
    int m = l & 15, quad = l >> 4;

    // Tmean as bf16 bits, register-resident (lanes 0..32)
    float tmf = Tm[l < TSZ ? l : 0];
    int tmb = (int)__builtin_bit_cast(unsigned short, (__bf16)tmf);

    // ---- stage Q tile (16 i-rows x 8 heads x 64 d) into LDS ----
    {
        int t = w * 64 + l;                  // 0..511, 1024 fragments total
        for (int f = t; f < 1024; f += 512) {
            int h = f & 7, qq = (f >> 3) & 7, i = f >> 6;
            Qt[i][qq][h] = *(const bf16x8*)(Qbf +
                ((size_t)(b * HH + h) * SS + i0 * 16 + i) * DK + qq * 8);
        }
    }
    __syncthreads();

    // ---- bias phase: wave w handles local j-tile w, all h, i = 0..15 ----
    {
        const int ISTR = SS * DK; // 32768
        const int* rbase = relpos + ((size_t)(b * SS + i0 * 16) * SS + jq * 128 + w * 16 + m) * DK + quad * 8;
        // depth-2 prefetch of relpos (HBM latency ~900cy), nontemporal (stream-once)
        i32x4 u0 = __builtin_nontemporal_load((const i32x4*)(rbase));
        i32x4 u1 = __builtin_nontemporal_load((const i32x4*)(rbase + 4));
        i32x4 u2 = __builtin_nontemporal_load((const i32x4*)(rbase + 32));
        i32x4 u3 = __builtin_nontemporal_load((const i32x4*)(rbase + 36));
        const int* pb1 = rbase + ISTR;
        i32x4 v0 = __builtin_nontemporal_load((const i32x4*)(pb1));
        i32x4 v1 = __builtin_nontemporal_load((const i32x4*)(pb1 + 4));
        i32x4 v2 = __builtin_nontemporal_load((const i32x4*)(pb1 + 32));
        i32x4 v3 = __builtin_nontemporal_load((const i32x4*)(pb1 + 36));
        for (int i = 0; i < 16; ++i) {
            i32x4 n0, n1, n2, n3;
            if (i < 14) {
                const int* nb = rbase + (i + 2) * ISTR;
                n0 = __builtin_nontemporal_load((const i32x4*)(nb));
                n1 = __builtin_nontemporal_load((const i32x4*)(nb + 4));
                n2 = __builtin_nontemporal_load((const i32x4*)(nb + 32));
                n3 = __builtin_nontemporal_load((const i32x4*)(nb + 36));
            }
            // A-frags from LDS (lgkmcnt path, not vmcnt)
            bf16x8 A0 = Qt[i][quad][m & 7];
            bf16x8 A1 = Qt[i][quad + 4][m & 7];
            // B-frags: Tm[clip(idx)] via bpermute LUT
#define LUT(vv) __builtin_amdgcn_ds_bpermute((min(max((vv), -PP), PP) + PP) << 2, tmb)
            U8 Bf0, Bf1;
            Bf0.u[0] = LUT(u0[0]) | (LUT(u0[1]) << 16);
            Bf0.u[1] = LUT(u0[2]) | (LUT(u0[3]) << 16);
            Bf0.u[2] = LUT(u1[0]) | (LUT(u1[1]) << 16);
            Bf0.u[3] = LUT(u1[2]) | (LUT(u1[3]) << 16);
            Bf1.u[0] = LUT(u2[0]) | (LUT(u2[1]) << 16);
            Bf1.u[1] = LUT(u2[2]) | (LUT(u2[3]) << 16);
            Bf1.u[2] = LUT(u3[0]) | (LUT(u3[1]) << 16);
            Bf1.u[3] = LUT(u3[2]) | (LUT(u3[3]) << 16);
#undef LUT
            f32x4 accB = {0.f, 0.f, 0.f, 0.f};
            accB = __builtin_amdgcn_mfma_f32_16x16x32_bf16(A0, Bf0.v, accB, 0, 0, 0);
            accB = __builtin_amdgcn_mfma_f32_16x16x32_bf16(A1, Bf1.v, accB, 0, 0, 0);
            if (quad < 2) {
#pragma unroll
                for (int r = 0; r < 4; ++r) {
                    int h = quad * 4 + r;   // 0..7
                    bias_sh[h * 2112 + i * 132 + w * 16 + m] = (__bf16)accB[r];
                }
            }
            u0 = v0; u1 = v1; u2 = v2; u3 = v3;
            v0 = n0; v1 = n1; v2 = n2; v3 = n3;
        }
    }

    // ---- score phase: wave w = head w ----
    const __bf16* qrow = Qbf + ((size_t)(b * HH + w) * SS + i0 * 16 + m) * DK + quad * 8;
    bf16x8 a0 = *(const bf16x8*)qrow;
    bf16x8 a1 = *(const bf16x8*)(qrow + 32);

    f32x4 acc[8];
#pragma unroll
    for (int jt = 0; jt < 8; ++jt) {
        const __bf16* krow = Kbf + ((size_t)(b * HH + w) * SS + jq * 128 + jt * 16 + m) * DK + quad * 8;
        bf16x8 b0 = *(const bf16x8*)krow;
        bf16x8 b1 = *(const bf16x8*)(krow + 32);
        f32x4 c = {0.f, 0.f, 0.f, 0.f};
        c = __builtin_amdgcn_mfma_f32_16x16x32_bf16(a0, b0, c, 0, 0, 0);
        c = __builtin_amdgcn_mfma_f32_16x16x32_bf16(a1, b1, c, 0, 0, 0);
        acc[jt] = c;
    }

    __syncthreads();   // bias_sh ready

    // ---- combine: scale + bias ----
#pragma unroll
    for (int jt = 0; jt < 8; ++jt) {
#pragma unroll
        for (int r = 0; r < 4; ++r) {
            float bv = (float)bias_sh[w * 2112 + (quad * 4 + r) * 132 + jt * 16 + m];
            acc[jt][r] = acc[jt][r] * 0.125f + bv;
        }
    }

    // ---- mask ----
#pragma unroll
    for (int jt = 0; jt < 8; ++jt) {
        int mv = mask[b * SS + jq * 128 + jt * 16 + m];
        if (mv == 0) {
#pragma unroll
            for (int r = 0; r < 4; ++r) acc[jt][r] = -1e9f;
        }
    }

    // ---- partial softmax over this quarter ----
#pragma unroll
    for (int r = 0; r < 4; ++r) {
        float mx = -1e30f;
#pragma unroll
        for (int jt = 0; jt < 8; ++jt) mx = fmaxf(mx, acc[jt][r]);
        mx = fmaxf(mx, __shfl_xor(mx, 1));
        mx = fmaxf(mx, __shfl_xor(mx, 2));
        mx = fmaxf(mx, __shfl_xor(mx, 4));
        mx = fmaxf(mx, __shfl_xor(mx, 8));
        float sum = 0.f;
#pragma unroll
        for (int jt = 0; jt < 8; ++jt) {
            float e = __expf(acc[jt][r] - mx);
            acc[jt][r] = e;
            sum += e;
        }
        sum += __shfl_xor(sum, 1);
        sum += __shfl_xor(sum, 2);
        sum += __shfl_xor(sum, 4);
        sum += __shfl_xor(sum, 8);
        if (m == 0) {
            int row = i0 * 16 + quad * 4 + r;
            pm[((size_t)(b * HH + w) * SS + row) * 4 + jq] = mx;
            pl[((size_t)(b * HH + w) * SS + row) * 4 + jq] = sum;
        }
    }

    // ---- store p' (unnormalized, bf16) ----
#pragma unroll
    for (int jt = 0; jt < 8; ++jt) {
#pragma unroll
        for (int r = 0; r < 4; ++r) {
            pws[((size_t)(b * HH + w) * SS + i0 * 16 + quad * 4 + r) * SS
                + jq * 128 + jt * 16 + m] = (__bf16)acc[jt][r];
        }
    }
}

// ---------------- F2: attn = scl*p' (f32 out) + ctx = P @ V, no LDS staging --------
__launch_bounds__(256, 4)
__global__ void f2_kernel(const __bf16* __restrict__ pws, const float* __restrict__ pm,
                          const float* __restrict__ pl, const __bf16* __restrict__ Vt,
                          float* __restrict__ attn, __bf16* __restrict__ ctx_bsd) {
    __shared__ float scl[4][16];

    int t = threadIdx.x;
    int l = t & 63, wv = t >> 6;
    int i0 = blockIdx.x, bh = blockIdx.y;

    if (t < 16) {
        int row = i0 * 16 + t;
        f32x4 m4 = *(const f32x4*)(pm + ((size_t)bh * SS + row) * 4);
        f32x4 l4 = *(const f32x4*)(pl + ((size_t)bh * SS + row) * 4);
        float M = fmaxf(fmaxf(m4[0], m4[1]), fmaxf(m4[2], m4[3]));
        float e0 = __expf(m4[0] - M), e1 = __expf(m4[1] - M);
        float e2 = __expf(m4[2] - M), e3 = __expf(m4[3] - M);
        float L = l4[0] * e0 + l4[1] * e1 + l4[2] * e2 + l4[3] * e3;
        float inv = 1.f / L;
        scl[0][t] = e0 * inv; scl[1][t] = e1 * inv;
        scl[2][t] = e2 * inv; scl[3][t] = e3 * inv;
    }
    __syncthreads();

    const __bf16* pbase = pws + ((size_t)bh * SS + i0 * 16) * SS;
    float* abase = attn + ((size_t)bh * SS + i0 * 16) * SS;

    // ---- phase C: final attn write (nontemporal, never re-read) ----
    int colq = l >> 4;   // 8 cols per lane stay within one j-quarter
#pragma unroll
    for (int rr = 0; rr < 4; ++rr) {
        int row = wv * 4 + rr;
        bf16x8 p = *(const bf16x8*)(pbase + (size_t)row * SS + l * 8);
        float s = scl[colq][row];
        f32x4 o0, o1;
        o0[0] = (float)p[0] * s; o0[1] = (float)p[1] * s;
        o0[2] = (float)p[2] * s; o0[3] = (float)p[3] * s;
        o1[0] = (float)p[4] * s; o1[1] = (float)p[5] * s;
        o1[2] = (float)p[6] * s; o1[3] = (float)p[7] * s;
        __builtin_nontemporal_store(o0, (f32x4*)(abase + (size_t)row * SS + l * 8));
        __builtin_nontemporal_store(o1, (f32x4*)(abase + (size_t)row * SS + l * 8 + 4));
    }

    // ---- phase B: PV with per-quarter accumulators ----
    int m = l & 15, quad = l >> 4;
    const __bf16* prow = pbase + (size_t)m * SS + quad * 8;
    const __bf16* vrow = Vt + ((size_t)bh * DK + wv * 16 + m) * SS + quad * 8;
    float ctxv[4] = {0.f, 0.f, 0.f, 0.f};
#pragma unroll
    for (int q = 0; q < 4; ++q) {
        f32x4 acc = {0.f, 0.f, 0.f, 0.f};
#pragma unroll
        for (int kk = 0; kk < 4; ++kk) {
            int k0 = q * 128 + kk * 32;
            bf16x8 aF = *(const bf16x8*)(prow + k0);
            bf16x8 bF = *(const bf16x8*)(vrow + k0);
            acc = __builtin_amdgcn_mfma_f32_16x16x32_bf16(aF, bF, acc, 0, 0, 0);
        }
#pragma unroll
        for (int r = 0; r < 4; ++r) ctxv[r] += acc[r] * scl[q][quad * 4 + r];
    }
    int b = bh >> 3, h = bh & 7;
#pragma unroll
    for (int r = 0; r < 4; ++r) {
        ctx_bsd[((size_t)(b * SS + i0 * 16 + quad * 4 + r)) * DD + h * DK + wv * 16 + m]
            = (__bf16)ctxv[r];
    }
}

// ---------------- fused: x = ctx @ Wo^T + bo + query, then LayerNorm -> y ----------
__launch_bounds__(512, 2)
__global__ void outln_kernel(const __bf16* __restrict__ Xc, const __bf16* __restrict__ Wobf,
                             const float* __restrict__ bo, const float* __restrict__ query,
                             const float* __restrict__ gamma, const float* __restrict__ beta,
                             float* __restrict__ y) {
    __shared__ float xsh[16 * 516];

    int lane = threadIdx.x, w = threadIdx.y;
    int tm = blockIdx.x;
    int m = lane & 15, quad = lane >> 4;

    const __bf16* arow = Xc + (size_t)(tm * 16 + m) * DD + quad * 8;

    f32x4 acc[4] = {{0.f,0.f,0.f,0.f},{0.f,0.f,0.f,0.f},{0.f,0.f,0.f,0.f},{0.f,0.f,0.f,0.f}};
    for (int k0 = 0; k0 < DD; k0 += 32) {
        bf16x8 a = *(const bf16x8*)(arow + k0);
#pragma unroll
        for (int tile = 0; tile < 4; ++tile) {
            const __bf16* brow = Wobf + (size_t)(w * 64 + tile * 16 + m) * DD + k0 + quad * 8;
            bf16x8 b = *(const bf16x8*)brow;
            acc[tile] = __builtin_amdgcn_mfma_f32_16x16x32_bf16(a, b, acc[tile], 0, 0, 0);
        }
    }

#pragma unroll
    for (int tile = 0; tile < 4; ++tile) {
        int col = w * 64 + tile * 16 + m;
        float bv = bo[col];
#pragma unroll
        for (int r = 0; r < 4; ++r) {
            int row = quad * 4 + r;
            int rowg = tm * 16 + row;
            xsh[row * 516 + col] = acc[tile][r] + bv + query[(size_t)rowg * DD + col];
        }
    }
    __syncthreads();

    // LN: wave w -> rows 2w, 2w+1; lane covers 8 cols
#pragma unroll
    for (int rr = 0; rr < 2; ++rr) {
        int row = w * 2 + rr;
        const float* xr = &xsh[row * 516];
        f32x4 xa = *(const f32x4*)(xr + lane * 8);
        f32x4 xb = *(const f32x4*)(xr + lane * 8 + 4);
        float s  = xa[0] + xa[1] + xa[2] + xa[3] + xb[0] + xb[1] + xb[2] + xb[3];
        float sq = xa[0]*xa[0] + xa[1]*xa[1] + xa[2]*xa[2] + xa[3]*xa[3]
                 + xb[0]*xb[0] + xb[1]*xb[1] + xb[2]*xb[2] + xb[3]*xb[3];
#pragma unroll
        for (int off = 32; off >= 1; off >>= 1) {
            s  += __shfl_xor(s, off);
            sq += __shfl_xor(sq, off);
        }
        float mu = s * (1.f / DD);
        float var = sq * (1.f / DD) - mu * mu;
        float inv = rsqrtf(var + 1e-5f);
        f32x4 g0 = *(const f32x4*)(gamma + lane * 8);
        f32x4 g1 = *(const f32x4*)(gamma + lane * 8 + 4);
        f32x4 b0 = *(const f32x4*)(beta + lane * 8);
        f32x4 b1 = *(const f32x4*)(beta + lane * 8 + 4);
        f32x4 o0, o1;
#pragma unroll
        for (int e = 0; e < 4; ++e) {
            o0[e] = (xa[e] - mu) * inv * g0[e] + b0[e];
            o1[e] = (xb[e] - mu) * inv * g1[e] + b1[e];
        }
        float* yr = y + (size_t)(tm * 16 + row) * DD + lane * 8;
        *(f32x4*)yr = o0;
        *(f32x4*)(yr + 4) = o1;
    }
}

extern "C" void kernel_launch(void* const* d_in, const int* in_sizes, int n_in,
                              void* d_out, int out_size, void* d_ws, size_t ws_size,
                              hipStream_t stream) {
    const float* query  = (const float*)d_in[0];
    const float* key    = (const float*)d_in[1];
    const float* value  = (const float*)d_in[2];
    const float* Wq     = (const float*)d_in[3];
    const float* bq     = (const float*)d_in[4];
    const float* Wk     = (const float*)d_in[5];
    const float* bk     = (const float*)d_in[6];
    const float* Wv     = (const float*)d_in[7];
    const float* bv     = (const float*)d_in[8];
    const float* Wo     = (const float*)d_in[9];
    const float* bo     = (const float*)d_in[10];
    const float* rtab   = (const float*)d_in[11];
    const float* gamma  = (const float*)d_in[12];
    const float* beta   = (const float*)d_in[13];
    const int*   mask   = (const int*)d_in[14];
    const int*   relpos = (const int*)d_in[15];

    float* out = (float*)d_out;
    float* y    = out;
    float* attn = out + (size_t)BB * SS * DD;

    char* wsb = (char*)d_ws;
    float*  Tm    = (float*)wsb;   wsb += 256;
    __bf16* Qbf   = (__bf16*)wsb;  wsb += (size_t)BB * HH * SS * DK * 2;
    __bf16* Kbf   = (__bf16*)wsb;  wsb += (size_t)BB * HH * SS * DK * 2;
    __bf16* Vtbf  = (__bf16*)wsb;  wsb += (size_t)BB * HH * DK * SS * 2;
    __bf16* ctxbf = (__bf16*)wsb;  wsb += (size_t)BB * SS * DD * 2;
    __bf16* Wqb   = (__bf16*)wsb;  wsb += (size_t)DD * DD * 2;
    __bf16* Wkb   = (__bf16*)wsb;  wsb += (size_t)DD * DD * 2;
    __bf16* Wvb   = (__bf16*)wsb;  wsb += (size_t)DD * DD * 2;
    __bf16* Wob   = (__bf16*)wsb;  wsb += (size_t)DD * DD * 2;
    __bf16* qb    = (__bf16*)wsb;  wsb += (size_t)BB * SS * DD * 2;
    __bf16* kb    = (__bf16*)wsb;  wsb += (size_t)BB * SS * DD * 2;
    __bf16* vb    = (__bf16*)wsb;  wsb += (size_t)BB * SS * DD * 2;
    __bf16* pws   = (__bf16*)wsb;  wsb += (size_t)BB * HH * SS * SS * 2;
    float*  pm    = (float*)wsb;   wsb += (size_t)BB * HH * SS * 4 * 4;
    float*  pl    = (float*)wsb;   wsb += (size_t)BB * HH * SS * 4 * 4;

    hipLaunchKernelGGL(prep_kernel, dim3(2049), dim3(256), 0, stream,
                       rtab, Tm, Wq, Wk, Wv, Wo, query, key, value,
                       Wqb, Wkb, Wvb, Wob, qb, kb, vb);

    hipLaunchKernelGGL(proj_mfma_kernel, dim3(DD / 64, (BB * SS) / 64, 3), dim3(64, 4), 0, stream,
                       qb, kb, vb, Wqb, Wkb, Wvb, bq, bk, bv, Qbf, Kbf, Vtbf);

    hipLaunchKernelGGL(f1_kernel, dim3(4, SS / 16, BB), dim3(64, 8), 0, stream,
                       Qbf, Kbf, relpos, Tm, mask, pws, pm, pl);

    hipLaunchKernelGGL(f2_kernel, dim3(SS / 16, BB * HH), dim3(256), 0, stream,
                       pws, pm, pl, Vtbf, attn, ctxbf);

    hipLaunchKernelGGL(outln_kernel, dim3((BB * SS) / 16), dim3(64, 8), 0, stream,
                       ctxbf, Wob, bo, query, gamma, beta, y);
}